// Round 2
// baseline (88.143 us; speedup 1.0000x reference)
//
#include <hip/hip_runtime.h>

// OptimalTransportDepthLoss: B=65536 rows of D=256.
// loss = mean_b [ mean_i (P-Q)^2  +  EMD2(P/sumP, Q/sumQ) ]
// EMD2 via stable merge of the two CDFs (equivalent to the reference's
// sort + searchsorted-at-midpoints construction):
//   cp[i] at merged pos i + #{cq < cp[i]}  -> segment (prev, cp[i]], ip=i, iq=#{cq<cp[i]}
//   cq[j] at merged pos j + #{cp <= cq[j]} -> segment (prev, cq[j]], iq=j, ip=#{cp<=cq[j]}
// Positions are a bijection onto 0..511; tie segments get dt=0 (contribute 0).
// Cross-row accumulation in f64 (f32 tree at sum~3.2e7 loses ~20-70 abs vs
// the f64 numpy reference; threshold is 0.575).

#define NW    4      // waves per block
#define DSZ   256    // histogram length
#define NSEG  512    // merged breakpoints

__device__ __forceinline__ int lower256(const float* a, float v) {
    // count of elements < v, in [0,256]
    int lo = 0, hi = 256;
#pragma unroll
    for (int k = 0; k < 8; ++k) {
        int mid = (lo + hi) >> 1;
        bool c = a[mid] < v;
        lo = c ? (mid + 1) : lo;
        hi = c ? hi : mid;
    }
    return lo;
}

__device__ __forceinline__ int upper256(const float* a, float v) {
    // count of elements <= v, in [0,256]
    int lo = 0, hi = 256;
#pragma unroll
    for (int k = 0; k < 8; ++k) {
        int mid = (lo + hi) >> 1;
        bool c = a[mid] <= v;
        lo = c ? (mid + 1) : lo;
        hi = c ? hi : mid;
    }
    return lo;
}

__global__ __launch_bounds__(256) void otdl_main(
    const float* __restrict__ P, const float* __restrict__ Q,
    double* __restrict__ partial, int B, int bpw)
{
    __shared__ float  s_cp[NW][DSZ];
    __shared__ float  s_cq[NW][DSZ];
    __shared__ float  s_mg[NW][NSEG];
    __shared__ double s_bsum[NW];

    const int tid  = threadIdx.x;
    const int wv   = tid >> 6;
    const int lane = tid & 63;
    const int wgl  = blockIdx.x * NW + wv;   // global wave id

    float* cp = s_cp[wv];
    float* cq = s_cq[wv];
    float* mg = s_mg[wv];

    double acc = 0.0;

    for (int it = 0; it < bpw; ++it) {
        int b = wgl * bpw + it;
        bool valid = (b < B);
        int bc = valid ? b : (B - 1);

        const float4* Pr = reinterpret_cast<const float4*>(P + (size_t)bc * DSZ);
        const float4* Qr = reinterpret_cast<const float4*>(Q + (size_t)bc * DSZ);
        float4 pv = Pr[lane];
        float4 qv = Qr[lane];

        // MSE partial (raw P,Q)
        float dx = pv.x - qv.x, dy = pv.y - qv.y;
        float dz = pv.z - qv.z, dw = pv.w - qv.w;
        float msel = dx*dx + dy*dy + dz*dz + dw*dw;

        // lane-local sums
        float pl = pv.x + pv.y + pv.z + pv.w;
        float ql = qv.x + qv.y + qv.z + qv.w;

        // wave inclusive scan of lane sums
        float ps = pl, qs = ql;
#pragma unroll
        for (int off = 1; off < 64; off <<= 1) {
            float tp = __shfl_up(ps, off, 64);
            float tq = __shfl_up(qs, off, 64);
            ps += (lane >= off) ? tp : 0.0f;
            qs += (lane >= off) ? tq : 0.0f;
        }
        float ptot = __shfl(ps, 63, 64);
        float qtot = __shfl(qs, 63, 64);
        float rp = 1.0f / ptot;
        float rq = 1.0f / qtot;
        float pe = ps - pl;   // exclusive prefix for this lane
        float qe = qs - ql;

        // per-element normalized cumsum values (monotone nondecreasing)
        float vP[4], vQ[4];
        vP[0] = (pe + pv.x) * rp;
        vP[1] = (pe + pv.x + pv.y) * rp;
        vP[2] = (pe + pv.x + pv.y + pv.z) * rp;
        vP[3] = ps * rp;
        vQ[0] = (qe + qv.x) * rq;
        vQ[1] = (qe + qv.x + qv.y) * rq;
        vQ[2] = (qe + qv.x + qv.y + qv.z) * rq;
        vQ[3] = qs * rq;

        __syncthreads();   // previous iteration's LDS readers are done
        int base = lane * 4;
#pragma unroll
        for (int e = 0; e < 4; ++e) { cp[base + e] = vP[e]; cq[base + e] = vQ[e]; }
        __syncthreads();

        // ranks -> merged positions + index differences
        int posP[4], posQ[4];
        float dP[4], dQ[4];
#pragma unroll
        for (int e = 0; e < 4; ++e) {
            int i = base + e;
            int c = lower256(cq, vP[e]);      // #cq < v  (cp wins ties)
            posP[e] = i + c;
            int iq = (c > 255) ? 255 : c;
            dP[e] = (float)(i - iq);
            int d = upper256(cp, vQ[e]);      // #cp <= v
            posQ[e] = i + d;
            int ip = (d > 255) ? 255 : d;
            dQ[e] = (float)(ip - i);
        }

        // scatter merged values (bijection onto 0..511)
#pragma unroll
        for (int e = 0; e < 4; ++e) {
            mg[posP[e]] = vP[e];
            mg[posQ[e]] = vQ[e];
        }
        __syncthreads();

        // each element owns its segment: dt = t_k - t_{k-1}
        float emdl = 0.0f;
#pragma unroll
        for (int e = 0; e < 4; ++e) {
            float tp = posP[e] ? mg[posP[e] - 1] : 0.0f;
            emdl += (vP[e] - tp) * dP[e] * dP[e];
            float tq = posQ[e] ? mg[posQ[e] - 1] : 0.0f;
            emdl += (vQ[e] - tq) * dQ[e] * dQ[e];
        }

        if (valid) acc += (double)(emdl + msel * (1.0f / 256.0f));
    }

    // wave reduce (f64 via two f32-shuffles per step)
#pragma unroll
    for (int off = 32; off; off >>= 1) {
        double o = __shfl_xor(acc, off, 64);
        acc += o;
    }
    if (lane == 0) s_bsum[wv] = acc;
    __syncthreads();
    if (tid == 0) {
        partial[blockIdx.x] = s_bsum[0] + s_bsum[1] + s_bsum[2] + s_bsum[3];
    }
}

__global__ __launch_bounds__(256) void otdl_reduce(
    const double* __restrict__ partial, int n, float* __restrict__ out, double invB)
{
    __shared__ double sdata[256];
    double a = 0.0;
    for (int i = threadIdx.x; i < n; i += 256) a += partial[i];
    sdata[threadIdx.x] = a;
    __syncthreads();
    for (int s2 = 128; s2 > 0; s2 >>= 1) {
        if (threadIdx.x < s2) sdata[threadIdx.x] += sdata[threadIdx.x + s2];
        __syncthreads();
    }
    if (threadIdx.x == 0) out[0] = (float)(sdata[0] * invB);
}

extern "C" void kernel_launch(void* const* d_in, const int* in_sizes, int n_in,
                              void* d_out, int out_size, void* d_ws, size_t ws_size,
                              hipStream_t stream)
{
    const float* P = (const float*)d_in[0];
    const float* Q = (const float*)d_in[1];
    float* out = (float*)d_out;
    double* partial = (double*)d_ws;

    int B = in_sizes[0] / DSZ;          // 65536
    const int blocks = 2048;
    const int totalWaves = blocks * NW; // 8192
    int bpw = (B + totalWaves - 1) / totalWaves;  // 8

    otdl_main<<<blocks, 256, 0, stream>>>(P, Q, partial, B, bpw);
    otdl_reduce<<<1, 256, 0, stream>>>(partial, blocks, out, 1.0 / (double)B);
}

// Round 3
// 47.940 us; speedup vs baseline: 1.8386x; 1.8386x over previous
//
#include <hip/hip_runtime.h>

// OptimalTransportDepthLoss: B=65536 rows of D=256.
// loss = mean_b [ mean_i (P-Q)^2 + EMD2(P/sumP, Q/sumQ) ]
//
// EMD2 closed form (no merged-segment bookkeeping needed):
//   ip(t) = sum_{i<=254} 1[cp_i < t]  (clip inactive in the interior), so
//   EMD2 = sum_{i<=254} cp_i (2*u^_i - 2i - 1) + sum_{j<=254} cq_j (2*l^_j - 2j - 1)
//   with u^_i = min(#{cq <= cp_i}, 255),  l^_j = min(#{cp < cq_j}, 255).
// A stable merge with cq-priority (emit cq when cq <= cp) yields both ranks:
// at cp_i's emission j = #{cq <= cp_i}; at cq_j's emission i = #{cp < cq_j}.
// Each lane merges 8 of the 512 outputs: merge-path diagonal search (9 steps)
// + 8 merge steps reading heads from LDS. Cross-row accumulation in f64.

#define NW    4      // waves per block
#define DSZ   256    // histogram length
#define LROW  264    // padded LDS row (256 vals + sentinel at [256])

__global__ __launch_bounds__(256) void otdl_main(
    const float* __restrict__ P, const float* __restrict__ Q,
    double* __restrict__ partial, int B, int bpw)
{
    __shared__ float  s_cp[NW][LROW];
    __shared__ float  s_cq[NW][LROW];
    __shared__ double s_bsum[NW];

    const int tid  = threadIdx.x;
    const int wv   = tid >> 6;
    const int lane = tid & 63;
    const int wgl  = blockIdx.x * NW + wv;   // global wave id

    float* cp = s_cp[wv];
    float* cq = s_cq[wv];

    // +inf sentinels at index 256 (real values are <= ~1.0); written once,
    // only this wave reads them, barriers in the loop order the accesses.
    if (lane == 0) { cp[DSZ] = 2.0f; cq[DSZ] = 2.0f; }

    double acc = 0.0;
    const int k0 = lane * 8;                 // this lane's merge-path diagonal

    for (int it = 0; it < bpw; ++it) {
        int b = wgl * bpw + it;
        bool valid = (b < B);
        int bc = valid ? b : (B - 1);

        const float4* Pr = reinterpret_cast<const float4*>(P + (size_t)bc * DSZ);
        const float4* Qr = reinterpret_cast<const float4*>(Q + (size_t)bc * DSZ);
        float4 pv = Pr[lane];
        float4 qv = Qr[lane];

        // MSE partial (raw P,Q)
        float dx = pv.x - qv.x, dy = pv.y - qv.y;
        float dz = pv.z - qv.z, dw = pv.w - qv.w;
        float msel = dx*dx + dy*dy + dz*dz + dw*dw;

        // lane-local sums
        float pl = pv.x + pv.y + pv.z + pv.w;
        float ql = qv.x + qv.y + qv.z + qv.w;

        // wave inclusive scan of lane sums
        float ps = pl, qs = ql;
#pragma unroll
        for (int off = 1; off < 64; off <<= 1) {
            float tp = __shfl_up(ps, off, 64);
            float tq = __shfl_up(qs, off, 64);
            ps += (lane >= off) ? tp : 0.0f;
            qs += (lane >= off) ? tq : 0.0f;
        }
        float ptot = __shfl(ps, 63, 64);
        float qtot = __shfl(qs, 63, 64);
        float rp = 1.0f / ptot;
        float rq = 1.0f / qtot;
        float pe = ps - pl;   // exclusive prefix
        float qe = qs - ql;

        // normalized cumsums (monotone nondecreasing, last ~= 1.0)
        float vP[4], vQ[4];
        vP[0] = (pe + pv.x) * rp;
        vP[1] = (pe + pv.x + pv.y) * rp;
        vP[2] = (pe + pv.x + pv.y + pv.z) * rp;
        vP[3] = ps * rp;
        vQ[0] = (qe + qv.x) * rq;
        vQ[1] = (qe + qv.x + qv.y) * rq;
        vQ[2] = (qe + qv.x + qv.y + qv.z) * rq;
        vQ[3] = qs * rq;

        __syncthreads();   // previous iteration's LDS readers are done
        int base = lane * 4;
#pragma unroll
        for (int e = 0; e < 4; ++e) { cp[base + e] = vP[e]; cq[base + e] = vQ[e]; }
        __syncthreads();

        // ---- merge-path co-rank: smallest i in [lo,hi] with
        //      cq[k0-1-i] <= cp[i]  (cq[-1] = -inf true, cp[256] = +inf true)
        int lo = k0 > DSZ ? k0 - DSZ : 0;
        int hi = k0 < DSZ ? k0 : DSZ;
#pragma unroll
        for (int s = 0; s < 9; ++s) {
            int mid = (lo + hi) >> 1;
            int jm1 = k0 - 1 - mid;
            int jr  = jm1 < 0 ? 0 : jm1;
            float cqv = cq[jr];
            float cpv = cp[mid];
            bool pred = (jm1 < 0) || (cqv <= cpv);
            hi = pred ? mid : hi;
            lo = pred ? lo  : mid + 1;
        }
        int i = lo;
        int j = k0 - lo;

        // ---- 8 merge steps (cq wins ties): rank formula accumulation
        float a  = cp[i];
        float b2 = cq[j];
        float emdl = 0.0f;
#pragma unroll
        for (int s = 0; s < 8; ++s) {
            bool  ea  = a < b2;            // emit cp only if strictly smaller
            float val = ea ? a : b2;
            int   own = ea ? i : j;
            int   oth = ea ? j : i;
            int   otc = oth > 255 ? 255 : oth;
            float coef = (own > 254) ? 0.0f : (float)(2 * otc - 2 * own - 1);
            emdl = fmaf(val, coef, emdl);
            i += ea ? 1 : 0;
            j += ea ? 0 : 1;
            a  = cp[i];                    // i,j <= 256 (sentinel), never both 256
            b2 = cq[j];
        }

        if (valid) acc += (double)(emdl + msel * (1.0f / 256.0f));
    }

    // wave reduce (f64)
#pragma unroll
    for (int off = 32; off; off >>= 1) {
        double o = __shfl_xor(acc, off, 64);
        acc += o;
    }
    if (lane == 0) s_bsum[wv] = acc;
    __syncthreads();
    if (tid == 0) {
        partial[blockIdx.x] = s_bsum[0] + s_bsum[1] + s_bsum[2] + s_bsum[3];
    }
}

__global__ __launch_bounds__(256) void otdl_reduce(
    const double* __restrict__ partial, int n, float* __restrict__ out, double invB)
{
    __shared__ double sdata[256];
    double a = 0.0;
    for (int i = threadIdx.x; i < n; i += 256) a += partial[i];
    sdata[threadIdx.x] = a;
    __syncthreads();
    for (int s2 = 128; s2 > 0; s2 >>= 1) {
        if (threadIdx.x < s2) sdata[threadIdx.x] += sdata[threadIdx.x + s2];
        __syncthreads();
    }
    if (threadIdx.x == 0) out[0] = (float)(sdata[0] * invB);
}

extern "C" void kernel_launch(void* const* d_in, const int* in_sizes, int n_in,
                              void* d_out, int out_size, void* d_ws, size_t ws_size,
                              hipStream_t stream)
{
    const float* P = (const float*)d_in[0];
    const float* Q = (const float*)d_in[1];
    float* out = (float*)d_out;
    double* partial = (double*)d_ws;

    int B = in_sizes[0] / DSZ;          // 65536
    const int blocks = 2048;
    const int totalWaves = blocks * NW; // 8192
    int bpw = (B + totalWaves - 1) / totalWaves;  // 8

    otdl_main<<<blocks, 256, 0, stream>>>(P, Q, partial, B, bpw);
    otdl_reduce<<<1, 256, 0, stream>>>(partial, blocks, out, 1.0 / (double)B);
}